// Round 9
// baseline (189.834 us; speedup 1.0000x reference)
//
#include <hip/hip_runtime.h>

// MpMaxPoolingMatch: out[b,t,m] = tanh( max_s sum_d lt[b,t,d]*km[m,d]*rt[b,s,d] )
// B=32, T=256, D=512, MP=20.
// R19: hoist the A-operand build OUT of the match kernel. R18 post-mortem:
// spill-free + 33% occupancy + unchanged 48us + MfmaUtil pinned 17% across 4
// structures -> match is phase-locked: A-staging (84M mul+cvt kernel-wide,
// VALUBusy 33%) + barrier + short MFMA bursts; waves stall in lockstep.
// Fix: workspace is ~268MB (poison fill = 2.685e8 B, fixed 45us), so precompute
//   ltf[b,m,t0-tile] = fp8(lt[b,t,d]*km[m,d])   (84 MB, tiled+swizzled)
// in the cast kernel (pure throughput, ~88MB writes). Match becomes:
//   32KB A-tile DMA via global_load_lds (4 instrs/wave, zero VALU)
//   -> ONE barrier -> pure MFMA K-loop (B reg-ring, lead-2) -> epilogue.
// LDS-conflict fix per rule 21: linear DMA dest + source written at
// byte^((row&3)<<5) + ds_read at the same XOR -> same ~2-way cost as the old
// stride-34 layout. MFMA operand bytes bitwise-identical to R13-R18.
// rtf path, XCD alignment (b%8 == XCD for both producer and consumer), R18
// 8-wave x (64t x 32s) tiling, epilogue: unchanged.

constexpr int TT = 256;   // T
constexpr int DD = 512;   // D
constexpr int NM = 20;    // MP
constexpr int NB = 32;    // B
constexpr int BM = 64;    // t-tile

typedef float f32x4 __attribute__((ext_vector_type(4)));
typedef int   i32x8 __attribute__((ext_vector_type(8)));

__device__ __forceinline__ unsigned pack_bf16(float lo, float hi) {
    unsigned ulo = __builtin_bit_cast(unsigned, lo);
    unsigned uhi = __builtin_bit_cast(unsigned, hi);
    return (ulo >> 16) | (uhi & 0xFFFF0000u);
}

// 4 fp32 -> 4 fp8 (e4m3, packed dword)
__device__ __forceinline__ unsigned pk4_fp8(float a, float b, float c, float d) {
    unsigned r = __builtin_amdgcn_cvt_pk_fp8_f32(a, b, 0, false);
    return __builtin_amdgcn_cvt_pk_fp8_f32(c, d, r, true);
}

// async global->LDS DMA, 16B/lane. LDS destination = wave-uniform base + lane*16.
__device__ __forceinline__ void gld_lds16(const void* g, void* l) {
    __builtin_amdgcn_global_load_lds(
        (const __attribute__((address_space(1))) void*)g,
        (__attribute__((address_space(3))) void*)l, 16, 0, 0);
}

// ================= Phase 1: build both fp8 operands (XCD-aligned) =================
// ltf layout: per (b,m,t0) a 32KB tile of 32B granules (row 0..63, c 0..15):
//   granule holds fp8(lt[b,t0+row,d]*km[m,d]) for d = c*32..+32 (natural order)
//   at tile byte (row*512 + c*32) ^ ((row&3)<<5)     [bank swizzle, rule 21]
// rtf layout (unchanged): 32B element e = (b*4096 + (kk*16+g)*64 + lane):
//   rt[b][s = g*16+(lane&15)][d = kk*128+(lane>>4)*32 .. +32] as fp8.
__global__ __launch_bounds__(256)
void cast_ops(const float* __restrict__ lt, const float* __restrict__ rt,
              const float* __restrict__ km,
              unsigned char* __restrict__ ltf, unsigned char* __restrict__ rtf)
{
    const int bid = (int)blockIdx.x;
    const int tid = threadIdx.x;
    if (bid < 10240) {
        // ---- lt*km -> ltf. 2.62M granules; one granule (32B) per thread.
        const int c8  = bid & 7;                 // XCD (flat%8)
        const int g   = bid >> 3;                // 0..1279
        const int b   = c8 + 8 * (g & 3);        // b%8 == XCD == consumer's XCD
        const int sub = g >> 2;                  // 0..319
        const int m   = sub >> 4;                // 0..19
        const int q   = sub & 15;
        const int ti  = q >> 2;                  // t0 index 0..3
        const int row = (q & 3) * 16 + (tid >> 4);  // 0..63
        const int c   = tid & 15;                // 0..15
        const int d0  = c * 32;

        const float* lp = lt + (((size_t)b * TT + ti * BM + row) * DD + d0);
        const float* kp = km + (size_t)m * DD + d0;
        uint4 w0, w1;
        {
            float4 x0 = *(const float4*)(lp);      float4 k0 = *(const float4*)(kp);
            float4 x1 = *(const float4*)(lp + 4);  float4 k1 = *(const float4*)(kp + 4);
            float4 x2 = *(const float4*)(lp + 8);  float4 k2 = *(const float4*)(kp + 8);
            float4 x3 = *(const float4*)(lp + 12); float4 k3 = *(const float4*)(kp + 12);
            w0.x = pk4_fp8(x0.x * k0.x, x0.y * k0.y, x0.z * k0.z, x0.w * k0.w);
            w0.y = pk4_fp8(x1.x * k1.x, x1.y * k1.y, x1.z * k1.z, x1.w * k1.w);
            w0.z = pk4_fp8(x2.x * k2.x, x2.y * k2.y, x2.z * k2.z, x2.w * k2.w);
            w0.w = pk4_fp8(x3.x * k3.x, x3.y * k3.y, x3.z * k3.z, x3.w * k3.w);
        }
        {
            float4 x0 = *(const float4*)(lp + 16); float4 k0 = *(const float4*)(kp + 16);
            float4 x1 = *(const float4*)(lp + 20); float4 k1 = *(const float4*)(kp + 20);
            float4 x2 = *(const float4*)(lp + 24); float4 k2 = *(const float4*)(kp + 24);
            float4 x3 = *(const float4*)(lp + 28); float4 k3 = *(const float4*)(kp + 28);
            w1.x = pk4_fp8(x0.x * k0.x, x0.y * k0.y, x0.z * k0.z, x0.w * k0.w);
            w1.y = pk4_fp8(x1.x * k1.x, x1.y * k1.y, x1.z * k1.z, x1.w * k1.w);
            w1.z = pk4_fp8(x2.x * k2.x, x2.y * k2.y, x2.z * k2.z, x2.w * k2.w);
            w1.w = pk4_fp8(x3.x * k3.x, x3.y * k3.y, x3.z * k3.z, x3.w * k3.w);
        }
        const size_t tbase = (((size_t)b * NM + m) * 4 + ti) * 32768;
        const int    lbyte = (row * 512 + c * 32) ^ ((row & 3) << 5);
        unsigned char* dst = ltf + tbase + lbyte;
        *(uint4*)dst        = w0;
        *(uint4*)(dst + 16) = w1;
    } else {
        // ---- rt -> rtf (identical to the proven cast_rt; bid-10240, 10240%8==0).
        const int bid2 = bid - 10240;          // 0..511
        const int c8   = bid2 & 7;
        const int i    = bid2 >> 3;            // 0..63
        const int b    = c8 + 8 * (i & 3);
        const int sub  = i >> 2;               // 0..15
        const int lane = tid & 63;
        const int u6   = sub * 4 + (tid >> 6); // 0..63 == kk*16 + g
        const int s    = (u6 & 15) * 16 + (lane & 15);
        const int d0   = (u6 >> 4) * 128 + (lane >> 4) * 32;

        const float* p = rt + ((size_t)b * TT + s) * DD + d0;
        float4 x0 = *(const float4*)p;
        float4 x1 = *(const float4*)(p + 4);
        float4 x2 = *(const float4*)(p + 8);
        float4 x3 = *(const float4*)(p + 12);
        float4 x4 = *(const float4*)(p + 16);
        float4 x5 = *(const float4*)(p + 20);
        float4 x6 = *(const float4*)(p + 24);
        float4 x7 = *(const float4*)(p + 28);
        uint4 w0, w1;
        w0.x = pk4_fp8(x0.x, x0.y, x0.z, x0.w);
        w0.y = pk4_fp8(x1.x, x1.y, x1.z, x1.w);
        w0.z = pk4_fp8(x2.x, x2.y, x2.z, x2.w);
        w0.w = pk4_fp8(x3.x, x3.y, x3.z, x3.w);
        w1.x = pk4_fp8(x4.x, x4.y, x4.z, x4.w);
        w1.y = pk4_fp8(x5.x, x5.y, x5.z, x5.w);
        w1.z = pk4_fp8(x6.x, x6.y, x6.z, x6.w);
        w1.w = pk4_fp8(x7.x, x7.y, x7.z, x7.w);
        unsigned char* dst = rtf + ((size_t)b * 4096 + (size_t)u6 * 64 + lane) * 32;
        *(uint4*)dst        = w0;
        *(uint4*)(dst + 16) = w1;
    }
}

// ======= Main: 8 waves x (64t x 32s), MX fp8 K=128, DMA'd A, pure-MFMA loop =======
__global__ __launch_bounds__(512, 4)
void mp_match_mx(const unsigned char* __restrict__ ltf, const unsigned char* __restrict__ rtf,
                 float* __restrict__ out)
{
    __shared__ __attribute__((aligned(16))) uint4 Ash[2048];      // 32 KB, linear (DMA dest)
    __shared__ __attribute__((aligned(16))) float maxbuf[8][BM];  // 2 KB

    // XCD swizzle: flat%8 == XCD; b%8 == XCD.
    const int f  = blockIdx.x;           // 0..2559
    const int c8 = f & 7;
    const int i  = f >> 3;               // 0..319
    const int b  = c8 + 8 * (i / 80);    // 0..31
    const int j  = i % 80;
    const int m  = j >> 2;               // 0..19
    const int ti = j & 3;                // t0 = ti*64

    const int tid  = threadIdx.x;        // 0..511
    const int w    = tid >> 6;           // wave id 0..7: owns s = w*32 .. +32
    const int lane = tid & 63;
    const int l15  = lane & 15;
    const int l4   = lane >> 4;

    const unsigned char* aG   = ltf + (((size_t)b * NM + m) * 4 + ti) * 32768;
    const unsigned char* rtB0 = rtf + (size_t)b * 131072 + (size_t)(w * 128 + lane) * 32;

    // ---- A-tile DMA: 32 KB in 32 x 1KB wave-instructions; wave w moves its 4KB.
#pragma unroll
    for (int r = 0; r < 4; ++r) {
        const int off = w * 4096 + r * 1024 + lane * 16;
        gld_lds16(aG + off, (char*)Ash + off);
    }

    i32x8 ring[3];
    auto loadB = [&](int u) {
        ring[u % 3] = *(const i32x8*)(rtB0 + (u >> 1) * 32768 + (u & 1) * 2048);
    };
    loadB(0); loadB(1);   // lead-2 prologue, in flight through the barrier

    __syncthreads();      // compiler emits vmcnt(0) before s_barrier -> DMA complete

    f32x4 acc[4][2] = {};   // [ii][jj]: t = ti*64+ii*16+row, s = w*32 + jj*16 + col
    i32x8 av[4];

#pragma unroll
    for (int u = 0; u < 8; ++u) {
        const int kk = u >> 1, jj = u & 1;
        if (u + 2 < 8) loadB(u + 2);   // lead-2; 3-slot ring caps in-flight
        if (jj == 0) {
            // A frags: row = ii*16+l15, 32B at byte (row*512 + (kk*4+l4)*32) ^ ((l15&3)<<5)
#pragma unroll
            for (int ii = 0; ii < 4; ++ii) {
                const int lbyte = (((ii * 16 + l15) * 512) + (kk * 4 + l4) * 32) ^ ((l15 & 3) << 5);
                av[ii] = *(const i32x8*)((const char*)Ash + lbyte);
            }
        }
        const i32x8 bv = ring[u % 3];
#pragma unroll
        for (int ii = 0; ii < 4; ++ii)
            acc[ii][jj] = __builtin_amdgcn_mfma_scale_f32_16x16x128_f8f6f4(
                av[ii], bv, acc[ii][jj], 0, 0, 0, 127, 0, 127);  // fmt=fp8, scales=1.0
    }

    // ---- Epilogue: max over s. C layout: col(s)=lane&15, row(t)=(lane>>4)*4+reg.
#pragma unroll
    for (int ii = 0; ii < 4; ++ii) {
        f32x4 v = acc[ii][0];
        v.x = fmaxf(v.x, acc[ii][1].x);
        v.y = fmaxf(v.y, acc[ii][1].y);
        v.z = fmaxf(v.z, acc[ii][1].z);
        v.w = fmaxf(v.w, acc[ii][1].w);
#pragma unroll
        for (int off = 1; off < 16; off <<= 1) {
            v.x = fmaxf(v.x, __shfl_xor(v.x, off, 64));
            v.y = fmaxf(v.y, __shfl_xor(v.y, off, 64));
            v.z = fmaxf(v.z, __shfl_xor(v.z, off, 64));
            v.w = fmaxf(v.w, __shfl_xor(v.w, off, 64));
        }
        if (l15 == 0)
            *(f32x4*)&maxbuf[w][ii * 16 + l4 * 4] = v;
    }
    __syncthreads();
    if (tid < BM) {
        float v0 = fmaxf(fmaxf(maxbuf[0][tid], maxbuf[1][tid]),
                         fmaxf(maxbuf[2][tid], maxbuf[3][tid]));
        float v1 = fmaxf(fmaxf(maxbuf[4][tid], maxbuf[5][tid]),
                         fmaxf(maxbuf[6][tid], maxbuf[7][tid]));
        out[((size_t)b * TT + ti * BM + tid) * NM + m] = tanhf(fmaxf(v0, v1));
    }
}

// ---------------- R1 fallback (no workspace): bf16 MFMA, fp32 register staging ----------------
typedef short bf16x8 __attribute__((ext_vector_type(8)));

__global__ __launch_bounds__(256, 2)
void mp_match_kernel(const float* __restrict__ lt, const float* __restrict__ rt,
                     const float* __restrict__ km, float* __restrict__ out)
{
    __shared__ __attribute__((aligned(16))) unsigned short Ash[2][4][128][8];
    __shared__ __attribute__((aligned(16))) unsigned short Bsh2[2][4][256][8];
    __shared__ __attribute__((aligned(16))) float maxbuf[2][128];

    const int ttile = blockIdx.x, m = blockIdx.y, b = blockIdx.z;
    const int t0 = ttile * 128;
    const int tid = threadIdx.x, wave = tid >> 6, lane = tid & 63;
    const int l15 = lane & 15, l4 = lane >> 4;
    const int wt = (wave & 1) * 64, wsi = wave >> 1;

    const float* ltp = lt + ((size_t)b * TT + t0) * DD;
    const float* rtp = rt + (size_t)b * TT * DD;
    const float* kmp = km + (size_t)m * DD;
    const int a_t = tid >> 1, a_h = tid & 1;

    f32x4 acc[4][8] = {};

    auto stage = [&](int kk, int buf) {
        const int d0 = kk * 32;
        const float* ap = ltp + (size_t)a_t * DD + d0 + a_h * 16;
        const float* kp = kmp + d0 + a_h * 16;
#pragma unroll
        for (int q = 0; q < 2; ++q) {
            float4 x0 = *(const float4*)(ap + q * 8);
            float4 x1 = *(const float4*)(ap + q * 8 + 4);
            float4 k0 = *(const float4*)(kp + q * 8);
            float4 k1 = *(const float4*)(kp + q * 8 + 4);
            uint4 wv;
            wv.x = pack_bf16(x0.x * k0.x, x0.y * k0.y);
            wv.y = pack_bf16(x0.z * k0.z, x0.w * k0.w);
            wv.z = pack_bf16(x1.x * k1.x, x1.y * k1.y);
            wv.w = pack_bf16(x1.z * k1.z, x1.w * k1.w);
            *(uint4*)&Ash[buf][a_h * 2 + q][a_t][0] = wv;
        }
        const float* bp = rtp + (size_t)tid * DD + d0;
#pragma unroll
        for (int p = 0; p < 4; ++p) {
            float4 y0 = *(const float4*)(bp + p * 8);
            float4 y1 = *(const float4*)(bp + p * 8 + 4);
            uint4 wv;
            wv.x = pack_bf16(y0.x, y0.y);
            wv.y = pack_bf16(y0.z, y0.w);
            wv.z = pack_bf16(y1.x, y1.y);
            wv.w = pack_bf16(y1.z, y1.w);
            *(uint4*)&Bsh2[buf][p][tid][0] = wv;
        }
    };

    stage(0, 0);
    for (int kk = 0; kk < 16; ++kk) {
        const int buf = kk & 1;
        __syncthreads();
        bf16x8 af[4], bfv[8];
#pragma unroll
        for (int i2 = 0; i2 < 4; ++i2)
            af[i2] = *(const bf16x8*)&Ash[buf][l4][wt + i2 * 16 + l15][0];
#pragma unroll
        for (int j2 = 0; j2 < 8; ++j2)
            bfv[j2] = *(const bf16x8*)&Bsh2[buf][l4][wsi * 128 + j2 * 16 + l15][0];
        if (kk + 1 < 16) stage(kk + 1, buf ^ 1);
#pragma unroll
        for (int i2 = 0; i2 < 4; ++i2)
#pragma unroll
            for (int j2 = 0; j2 < 8; ++j2)
                acc[i2][j2] = __builtin_amdgcn_mfma_f32_16x16x32_bf16(af[i2], bfv[j2], acc[i2][j2], 0, 0, 0);
    }
#pragma unroll
    for (int i2 = 0; i2 < 4; ++i2) {
        f32x4 v = acc[i2][0];
#pragma unroll
        for (int j2 = 1; j2 < 8; ++j2) {
            v.x = fmaxf(v.x, acc[i2][j2].x); v.y = fmaxf(v.y, acc[i2][j2].y);
            v.z = fmaxf(v.z, acc[i2][j2].z); v.w = fmaxf(v.w, acc[i2][j2].w);
        }
#pragma unroll
        for (int off = 1; off < 16; off <<= 1) {
            v.x = fmaxf(v.x, __shfl_xor(v.x, off, 64));
            v.y = fmaxf(v.y, __shfl_xor(v.y, off, 64));
            v.z = fmaxf(v.z, __shfl_xor(v.z, off, 64));
            v.w = fmaxf(v.w, __shfl_xor(v.w, off, 64));
        }
        if (l15 == 0) *(f32x4*)&maxbuf[wsi][wt + i2 * 16 + l4 * 4] = v;
    }
    __syncthreads();
    if (tid < 128) {
        float v = fmaxf(maxbuf[0][tid], maxbuf[1][tid]);
        out[((size_t)b * TT + t0 + tid) * NM + m] = tanhf(v);
    }
}

extern "C" void kernel_launch(void* const* d_in, const int* in_sizes, int n_in,
                              void* d_out, int out_size, void* d_ws, size_t ws_size,
                              hipStream_t stream) {
    const float* lt  = (const float*)d_in[0];   // (32,256,512) fp32
    const float* rt  = (const float*)d_in[1];   // (32,256,512) fp32
    const float* km  = (const float*)d_in[2];   // (20,512) fp32
    float*       out = (float*)d_out;           // (32,256,20) fp32

    const size_t ltfB = (size_t)NB * NM * TT * DD;   // 83,886,080 B fp8 (A pre-product)
    const size_t rtfB = (size_t)NB * TT * DD;        //  4,194,304 B fp8
    if (ws_size >= ltfB + rtfB) {                    // 88.1 MB (ws ~268 MB observed)
        unsigned char* ltf = (unsigned char*)d_ws;
        unsigned char* rtf = (unsigned char*)d_ws + ltfB;
        cast_ops<<<10752, 256, 0, stream>>>(lt, rt, km, ltf, rtf);
        mp_match_mx<<<2560, 512, 0, stream>>>(ltf, rtf, out);
    } else {
        mp_match_kernel<<<dim3(2, NM, NB), 256, 0, stream>>>(lt, rt, km, out);
    }
}

// Round 10
// 149.079 us; speedup vs baseline: 1.2734x; 1.2734x over previous
//
#include <hip/hip_runtime.h>

// MpMaxPoolingMatch: out[b,t,m] = tanh( max_s sum_d lt[b,t,d]*km[m,d]*rt[b,s,d] )
// B=32, T=256, D=512, MP=20.
// R20: operand-resident m-loop. R10-R18 invariant (MfmaUtil ~17%, 44-54us across
// 6 structures) is TRAFFIC, not occupancy: B re-loaded from L2 every step
// (320MB for a 4.2MB tensor; per-SIMD 4 waves x 2KB/step = ~580cy L2 return vs
// 138cy MFMA -> L2-stream-bound 4x = exactly 17-24% util). R19's ltf precompute
// made it worse (84MB write + 336MB lt re-read in cast: 90us). Fix both by
// residency:
//  * grid 256 = 1 block/CU (bijective over 8 XCDs). Block = 32t x 256s x ALL
//    20 m. 8 waves x (32t x 32s).
//  * B: wave's full working set = 16KB = 64 VGPRs, loaded ONCE (8 coalesced
//    32B-lane loads from rtf). B traffic 320MB -> 32MB; ZERO in the K-loop.
//  * lt: thread's slice = 32 floats = 16 regs (bf16 pairs), loaded ONCE.
//  * per m: staging flash (km x ltp -> fp8 -> 16KB Ash, XOR-swizzled) ->
//    barrier -> pure-reg K-loop (av from LDS, B from regs, 16 MFMA/wave)
//    -> epilogue -> barrier. 2 barriers/m. acc[2][2]=16 regs.
//  * regs: B 64 + ltp 16 + acc 16 + av 16 + transients ~40 -> ~170 < 256:
//    2 waves/SIMD spill-free (launch_bounds(512,2)). 8 waves/CU ~25% occupancy
//    is EXPECTED (structural), not a failure signal.
//  * Ash swizzle: granule g stored at g^(row&15) -> read classes (l4^l15)&3 =
//    4-way (1.58x, m136) vs linear 16-way.
// MFMA operand bytes / scales (e8m0=127) bitwise-identical to R13-R18.
// cast_rt (XCD-aligned, proven 7us) unchanged.

constexpr int TT = 256;   // T
constexpr int DD = 512;   // D
constexpr int NM = 20;    // MP
constexpr int NB = 32;    // B

typedef float f32x4 __attribute__((ext_vector_type(4)));
typedef int   i32x8 __attribute__((ext_vector_type(8)));

__device__ __forceinline__ unsigned pack_bf16(float lo, float hi) {
    unsigned ulo = __builtin_bit_cast(unsigned, lo);
    unsigned uhi = __builtin_bit_cast(unsigned, hi);
    return (ulo >> 16) | (uhi & 0xFFFF0000u);
}
__device__ __forceinline__ float blo(unsigned u) { return __builtin_bit_cast(float, u << 16); }
// hi bf16 without masking low bits: <0.4% perturbation, absorbed by fp8 quant + tanh
// (verified absmax 0.0 in R10-R13 which used this exact path).
__device__ __forceinline__ float bhi(unsigned u) { return __builtin_bit_cast(float, u); }

// 4 fp32 -> 4 fp8 (e4m3, packed dword)
__device__ __forceinline__ unsigned pk4_fp8(float a, float b, float c, float d) {
    unsigned r = __builtin_amdgcn_cvt_pk_fp8_f32(a, b, 0, false);
    return __builtin_amdgcn_cvt_pk_fp8_f32(c, d, r, true);
}

// ---------------- Phase 1: rt fp32 -> fp8, 32B-contiguous lane tiles, XCD-aligned ----
// rtf layout: 32B element e = (b*4096 + (kk*16+g)*64 + lane):
//   holds rt[b][s = g*16 + (lane&15)][d = kk*128 + (lane>>4)*32 .. +32] as fp8.
__global__ __launch_bounds__(256)
void cast_rt(const float* __restrict__ rt, unsigned char* __restrict__ rtf)
{
    const int bid = (int)blockIdx.x;       // 0..511
    const int c8  = bid & 7;               // this block's XCD (flat%8)
    const int i   = bid >> 3;              // 0..63
    const int b   = c8 + 8 * (i & 3);      // b%8 == c8 == consumer XCD
    const int sub = i >> 2;                // 0..15
    const int tid = threadIdx.x;
    const int lane = tid & 63;
    const int u6  = sub * 4 + (tid >> 6);  // 0..63 == kk*16 + g
    const int s   = (u6 & 15) * 16 + (lane & 15);
    const int d0  = (u6 >> 4) * 128 + (lane >> 4) * 32;

    const float* p = rt + ((size_t)b * TT + s) * DD + d0;
    float4 x0 = *(const float4*)p;
    float4 x1 = *(const float4*)(p + 4);
    float4 x2 = *(const float4*)(p + 8);
    float4 x3 = *(const float4*)(p + 12);
    float4 x4 = *(const float4*)(p + 16);
    float4 x5 = *(const float4*)(p + 20);
    float4 x6 = *(const float4*)(p + 24);
    float4 x7 = *(const float4*)(p + 28);
    uint4 w0, w1;
    w0.x = pk4_fp8(x0.x, x0.y, x0.z, x0.w);
    w0.y = pk4_fp8(x1.x, x1.y, x1.z, x1.w);
    w0.z = pk4_fp8(x2.x, x2.y, x2.z, x2.w);
    w0.w = pk4_fp8(x3.x, x3.y, x3.z, x3.w);
    w1.x = pk4_fp8(x4.x, x4.y, x4.z, x4.w);
    w1.y = pk4_fp8(x5.x, x5.y, x5.z, x5.w);
    w1.z = pk4_fp8(x6.x, x6.y, x6.z, x6.w);
    w1.w = pk4_fp8(x7.x, x7.y, x7.z, x7.w);
    unsigned char* dst = rtf + ((size_t)b * 4096 + (size_t)u6 * 64 + lane) * 32;
    *(uint4*)dst        = w0;
    *(uint4*)(dst + 16) = w1;
}

// ======= Main: 32t x 256s x 20m per block, B+lt register-resident, MX fp8 K=128 =======
__global__ __launch_bounds__(512, 2)
void mp_match_mx(const float* __restrict__ lt, const unsigned char* __restrict__ rtf,
                 const float* __restrict__ km, float* __restrict__ out)
{
    // Ash: 32 rows x 16 granules(32B), granule g stored at slot g^(row&15).
    __shared__ __attribute__((aligned(16))) unsigned char Ash[32 * 512];  // 16 KB
    __shared__ __attribute__((aligned(16))) float maxbuf[8][32];          // 1 KB

    // XCD swizzle: flat%8 == XCD; b%8 == XCD. 256 blocks = 8 XCD x 4 b' x 8 ti.
    const int f  = blockIdx.x;           // 0..255
    const int c8 = f & 7;
    const int b  = c8 + 8 * ((f >> 3) & 3);  // 0..31
    const int ti = f >> 5;               // 0..7, t0 = ti*32

    const int tid  = threadIdx.x;        // 0..511
    const int w    = tid >> 6;           // wave id 0..7: owns s = w*32 .. +32
    const int lane = tid & 63;
    const int l15  = lane & 15;
    const int l4   = lane >> 4;

    // ---- B prologue: wave's full B working set -> 64 VGPRs (8 x i32x8), ONCE.
    // step (kk,jj): s = w*32 + jj*16 + l15, d = kk*128 + l4*32 .. +32.
    const unsigned char* rtB0 = rtf + (size_t)b * 131072 + (size_t)(w * 128 + lane) * 32;
    i32x8 Breg[8];
#pragma unroll
    for (int kk = 0; kk < 4; ++kk)
#pragma unroll
        for (int jj = 0; jj < 2; ++jj)
            Breg[kk * 2 + jj] = *(const i32x8*)(rtB0 + kk * 32768 + jj * 2048);

    // ---- lt prologue: thread (row=tid>>4, c=tid&15) holds lt[b, ti*32+row, c*32..+32]
    // as 16 bf16-pair u32s, ONCE. (bf16 trunc verified in R10-R13, absmax 0.0.)
    const int row = tid >> 4, c = tid & 15;
    unsigned ltp[16];
    {
        const float* lp = lt + ((size_t)b * TT + ti * 32 + row) * DD + c * 32;
#pragma unroll
        for (int q = 0; q < 8; ++q) {
            float4 x = *(const float4*)(lp + q * 4);
            ltp[q * 2]     = pack_bf16(x.x, x.y);
            ltp[q * 2 + 1] = pack_bf16(x.z, x.w);
        }
    }
    unsigned char* dstA = Ash + row * 512 + (c ^ (row & 15)) * 32;   // swizzled slot

#pragma unroll 1
    for (int m = 0; m < NM; ++m) {
        // ---- staging flash: km[m] chunk x ltp -> fp8 granule -> Ash.
        {
            const float* kp = km + (size_t)m * DD + c * 32;
            const float4 kA = *(const float4*)(kp);
            const float4 kB = *(const float4*)(kp + 4);
            const float4 kC = *(const float4*)(kp + 8);
            const float4 kD = *(const float4*)(kp + 12);
            uint4 o;
            o.x = pk4_fp8(blo(ltp[0]) * kA.x, bhi(ltp[0]) * kA.y, blo(ltp[1]) * kA.z, bhi(ltp[1]) * kA.w);
            o.y = pk4_fp8(blo(ltp[2]) * kB.x, bhi(ltp[2]) * kB.y, blo(ltp[3]) * kB.z, bhi(ltp[3]) * kB.w);
            o.z = pk4_fp8(blo(ltp[4]) * kC.x, bhi(ltp[4]) * kC.y, blo(ltp[5]) * kC.z, bhi(ltp[5]) * kC.w);
            o.w = pk4_fp8(blo(ltp[6]) * kD.x, bhi(ltp[6]) * kD.y, blo(ltp[7]) * kD.z, bhi(ltp[7]) * kD.w);
            *(uint4*)dstA = o;
            const float4 kE = *(const float4*)(kp + 16);
            const float4 kF = *(const float4*)(kp + 20);
            const float4 kG = *(const float4*)(kp + 24);
            const float4 kH = *(const float4*)(kp + 28);
            o.x = pk4_fp8(blo(ltp[8])  * kE.x, bhi(ltp[8])  * kE.y, blo(ltp[9])  * kE.z, bhi(ltp[9])  * kE.w);
            o.y = pk4_fp8(blo(ltp[10]) * kF.x, bhi(ltp[10]) * kF.y, blo(ltp[11]) * kF.z, bhi(ltp[11]) * kF.w);
            o.z = pk4_fp8(blo(ltp[12]) * kG.x, bhi(ltp[12]) * kG.y, blo(ltp[13]) * kG.z, bhi(ltp[13]) * kG.w);
            o.w = pk4_fp8(blo(ltp[14]) * kH.x, bhi(ltp[14]) * kH.y, blo(ltp[15]) * kH.z, bhi(ltp[15]) * kH.w);
            *(uint4*)(dstA + 16) = o;
        }
        __syncthreads();   // Ash(m) ready (also: prev epilogue's maxbuf reads done)

        // ---- K-loop: pure registers + swizzled LDS A reads. 16 MFMA/wave.
        f32x4 acc[2][2] = {};   // [ii][jj]: t = ti*32+ii*16+row, s = w*32+jj*16+col
#pragma unroll
        for (int kk = 0; kk < 4; ++kk) {
            i32x8 av[2];
#pragma unroll
            for (int ii = 0; ii < 2; ++ii) {
                const int r2 = ii * 16 + l15;
                av[ii] = *(const i32x8*)(Ash + r2 * 512 + (((kk * 4 + l4) ^ l15) * 32));
            }
#pragma unroll
            for (int ii = 0; ii < 2; ++ii)
#pragma unroll
                for (int jj = 0; jj < 2; ++jj)
                    acc[ii][jj] = __builtin_amdgcn_mfma_scale_f32_16x16x128_f8f6f4(
                        av[ii], Breg[kk * 2 + jj], acc[ii][jj], 0, 0, 0, 127, 0, 127);
        }

        // ---- Epilogue(m): max over s. C layout: col(s)=lane&15, row(t)=(lane>>4)*4+reg.
#pragma unroll
        for (int ii = 0; ii < 2; ++ii) {
            f32x4 v = acc[ii][0];
            v.x = fmaxf(v.x, acc[ii][1].x);
            v.y = fmaxf(v.y, acc[ii][1].y);
            v.z = fmaxf(v.z, acc[ii][1].z);
            v.w = fmaxf(v.w, acc[ii][1].w);
#pragma unroll
            for (int off = 1; off < 16; off <<= 1) {
                v.x = fmaxf(v.x, __shfl_xor(v.x, off, 64));
                v.y = fmaxf(v.y, __shfl_xor(v.y, off, 64));
                v.z = fmaxf(v.z, __shfl_xor(v.z, off, 64));
                v.w = fmaxf(v.w, __shfl_xor(v.w, off, 64));
            }
            if (l15 == 0)
                *(f32x4*)&maxbuf[w][ii * 16 + l4 * 4] = v;
        }
        __syncthreads();   // maxbuf(m) ready; Ash reads done (safe to restage)
        if (tid < 32) {
            float v0 = fmaxf(fmaxf(maxbuf[0][tid], maxbuf[1][tid]),
                             fmaxf(maxbuf[2][tid], maxbuf[3][tid]));
            float v1 = fmaxf(fmaxf(maxbuf[4][tid], maxbuf[5][tid]),
                             fmaxf(maxbuf[6][tid], maxbuf[7][tid]));
            out[((size_t)b * TT + ti * 32 + tid) * NM + m] = tanhf(fmaxf(v0, v1));
        }
        // maxbuf WAR: next write is after next iteration's barrier A -> ordered.
    }
}

// ---------------- R1 fallback (no workspace): bf16 MFMA, fp32 register staging ----------------
typedef short bf16x8 __attribute__((ext_vector_type(8)));

__global__ __launch_bounds__(256, 2)
void mp_match_kernel(const float* __restrict__ lt, const float* __restrict__ rt,
                     const float* __restrict__ km, float* __restrict__ out)
{
    __shared__ __attribute__((aligned(16))) unsigned short Ash[2][4][128][8];
    __shared__ __attribute__((aligned(16))) unsigned short Bsh2[2][4][256][8];
    __shared__ __attribute__((aligned(16))) float maxbuf[2][128];

    const int ttile = blockIdx.x, m = blockIdx.y, b = blockIdx.z;
    const int t0 = ttile * 128;
    const int tid = threadIdx.x, wave = tid >> 6, lane = tid & 63;
    const int l15 = lane & 15, l4 = lane >> 4;
    const int wt = (wave & 1) * 64, wsi = wave >> 1;

    const float* ltp = lt + ((size_t)b * TT + t0) * DD;
    const float* rtp = rt + (size_t)b * TT * DD;
    const float* kmp = km + (size_t)m * DD;
    const int a_t = tid >> 1, a_h = tid & 1;

    f32x4 acc[4][8] = {};

    auto stage = [&](int kk, int buf) {
        const int d0 = kk * 32;
        const float* ap = ltp + (size_t)a_t * DD + d0 + a_h * 16;
        const float* kp = kmp + d0 + a_h * 16;
#pragma unroll
        for (int q = 0; q < 2; ++q) {
            float4 x0 = *(const float4*)(ap + q * 8);
            float4 x1 = *(const float4*)(ap + q * 8 + 4);
            float4 k0 = *(const float4*)(kp + q * 8);
            float4 k1 = *(const float4*)(kp + q * 8 + 4);
            uint4 wv;
            wv.x = pack_bf16(x0.x * k0.x, x0.y * k0.y);
            wv.y = pack_bf16(x0.z * k0.z, x0.w * k0.w);
            wv.z = pack_bf16(x1.x * k1.x, x1.y * k1.y);
            wv.w = pack_bf16(x1.z * k1.z, x1.w * k1.w);
            *(uint4*)&Ash[buf][a_h * 2 + q][a_t][0] = wv;
        }
        const float* bp = rtp + (size_t)tid * DD + d0;
#pragma unroll
        for (int p = 0; p < 4; ++p) {
            float4 y0 = *(const float4*)(bp + p * 8);
            float4 y1 = *(const float4*)(bp + p * 8 + 4);
            uint4 wv;
            wv.x = pack_bf16(y0.x, y0.y);
            wv.y = pack_bf16(y0.z, y0.w);
            wv.z = pack_bf16(y1.x, y1.y);
            wv.w = pack_bf16(y1.z, y1.w);
            *(uint4*)&Bsh2[buf][p][tid][0] = wv;
        }
    };

    stage(0, 0);
    for (int kk = 0; kk < 16; ++kk) {
        const int buf = kk & 1;
        __syncthreads();
        bf16x8 af[4], bfv[8];
#pragma unroll
        for (int i2 = 0; i2 < 4; ++i2)
            af[i2] = *(const bf16x8*)&Ash[buf][l4][wt + i2 * 16 + l15][0];
#pragma unroll
        for (int j2 = 0; j2 < 8; ++j2)
            bfv[j2] = *(const bf16x8*)&Bsh2[buf][l4][wsi * 128 + j2 * 16 + l15][0];
        if (kk + 1 < 16) stage(kk + 1, buf ^ 1);
#pragma unroll
        for (int i2 = 0; i2 < 4; ++i2)
#pragma unroll
            for (int j2 = 0; j2 < 8; ++j2)
                acc[i2][j2] = __builtin_amdgcn_mfma_f32_16x16x32_bf16(af[i2], bfv[j2], acc[i2][j2], 0, 0, 0);
    }
#pragma unroll
    for (int i2 = 0; i2 < 4; ++i2) {
        f32x4 v = acc[i2][0];
#pragma unroll
        for (int j2 = 1; j2 < 8; ++j2) {
            v.x = fmaxf(v.x, acc[i2][j2].x); v.y = fmaxf(v.y, acc[i2][j2].y);
            v.z = fmaxf(v.z, acc[i2][j2].z); v.w = fmaxf(v.w, acc[i2][j2].w);
        }
#pragma unroll
        for (int off = 1; off < 16; off <<= 1) {
            v.x = fmaxf(v.x, __shfl_xor(v.x, off, 64));
            v.y = fmaxf(v.y, __shfl_xor(v.y, off, 64));
            v.z = fmaxf(v.z, __shfl_xor(v.z, off, 64));
            v.w = fmaxf(v.w, __shfl_xor(v.w, off, 64));
        }
        if (l15 == 0) *(f32x4*)&maxbuf[wsi][wt + i2 * 16 + l4 * 4] = v;
    }
    __syncthreads();
    if (tid < 128) {
        float v = fmaxf(maxbuf[0][tid], maxbuf[1][tid]);
        out[((size_t)b * TT + t0 + tid) * NM + m] = tanhf(v);
    }
}

extern "C" void kernel_launch(void* const* d_in, const int* in_sizes, int n_in,
                              void* d_out, int out_size, void* d_ws, size_t ws_size,
                              hipStream_t stream) {
    const float* lt  = (const float*)d_in[0];   // (32,256,512) fp32
    const float* rt  = (const float*)d_in[1];   // (32,256,512) fp32
    const float* km  = (const float*)d_in[2];   // (20,512) fp32
    float*       out = (float*)d_out;           // (32,256,20) fp32

    const size_t rtfB = (size_t)NB * TT * DD;   // 4,194,304 B fp8 (lane-tiled)
    if (ws_size >= rtfB) {
        unsigned char* rtf = (unsigned char*)d_ws;
        cast_rt<<<512, 256, 0, stream>>>(rt, rtf);            // XCD-aligned, proven
        mp_match_mx<<<256, 512, 0, stream>>>(lt, rtf, km, out);  // 1 block/CU, m-loop
    } else {
        mp_match_kernel<<<dim3(2, NM, NB), 256, 0, stream>>>(lt, rt, km, out);
    }
}

// Round 11
// 109.100 us; speedup vs baseline: 1.7400x; 1.3664x over previous
//
#include <hip/hip_runtime.h>

// MpMaxPoolingMatch: out[b,t,m] = tanh( max_s sum_d lt[b,t,d]*km[m,d]*rt[b,s,d] )
// B=32, T=256, D=512, MP=20.
// R21 = R18 + wave de-phasing. Falsified so far: VALU-bound (R13), B-latency
// (R12/13), occupancy (R18: 2->4 waves/SIMD, delta 0), operand traffic (R20:
// B fully reg-resident, WORSE). Remaining consistent explanation for MfmaUtil
// pinned ~17% across 7 structures: PHASE-LOCK -- all waves run the identical
// post-barrier instruction stream, so all 4 waves/SIMD contend for the matrix
// pipe in the same ~138cy window, then all idle together through the same
// load window; TLP hides nothing between synchronized replicas (m114 overlap
// needs phase-diverse waves; T5 catalog: setprio needs role-diversity).
// Changes vs R18 (otherwise byte-identical, proven absmax 0.0):
//  1) wave-rotated K-loop: u = (v + ofs)&7, ofs = 2*((w + (w>>2))&3) --
//     parity-preserving (jj/acc mapping unchanged), same-SIMD wave pairs
//     (w,w+4) get different offsets -> MFMA bursts staggered ~2 steps.
//     kk-accumulation order is reorder-safe (fp32 adds, fp8-quantized data).
//  2) s_setprio(1) around each 4-MFMA cluster (T5, prereq now satisfied).
// rtf layout, cast_rt, Ash stride 34, MFMA operand bytes/scales (e8m0=127),
// epilogue: identical to R18.

constexpr int TT = 256;   // T
constexpr int DD = 512;   // D
constexpr int NM = 20;    // MP
constexpr int NB = 32;    // B
constexpr int BM = 64;    // t-tile

typedef float f32x4 __attribute__((ext_vector_type(4)));
typedef int   i32x8 __attribute__((ext_vector_type(8)));

__device__ __forceinline__ unsigned pack_bf16(float lo, float hi) {
    unsigned ulo = __builtin_bit_cast(unsigned, lo);
    unsigned uhi = __builtin_bit_cast(unsigned, hi);
    return (ulo >> 16) | (uhi & 0xFFFF0000u);
}

// 4 fp32 -> 4 fp8 (e4m3, packed dword)
__device__ __forceinline__ unsigned pk4_fp8(float a, float b, float c, float d) {
    unsigned r = __builtin_amdgcn_cvt_pk_fp8_f32(a, b, 0, false);
    return __builtin_amdgcn_cvt_pk_fp8_f32(c, d, r, true);
}

// ---------------- Phase 1: rt fp32 -> fp8, 32B-contiguous lane tiles, XCD-aligned ----
// rtf layout: 32B element e = (b*4096 + (kk*16+g)*64 + lane):
//   holds rt[b][s = g*16 + (lane&15)][d = kk*128 + (lane>>4)*32 .. +32] as fp8.
__global__ __launch_bounds__(256)
void cast_rt(const float* __restrict__ rt, unsigned char* __restrict__ rtf)
{
    const int bid = (int)blockIdx.x;       // 0..511
    const int c8  = bid & 7;               // this block's XCD (flat%8)
    const int i   = bid >> 3;              // 0..63
    const int b   = c8 + 8 * (i & 3);      // b%8 == c8 == consumer XCD
    const int sub = i >> 2;                // 0..15
    const int tid = threadIdx.x;
    const int lane = tid & 63;
    const int u6  = sub * 4 + (tid >> 6);  // 0..63 == kk*16 + g
    const int s   = (u6 & 15) * 16 + (lane & 15);
    const int d0  = (u6 >> 4) * 128 + (lane >> 4) * 32;

    const float* p = rt + ((size_t)b * TT + s) * DD + d0;
    float4 x0 = *(const float4*)p;
    float4 x1 = *(const float4*)(p + 4);
    float4 x2 = *(const float4*)(p + 8);
    float4 x3 = *(const float4*)(p + 12);
    float4 x4 = *(const float4*)(p + 16);
    float4 x5 = *(const float4*)(p + 20);
    float4 x6 = *(const float4*)(p + 24);
    float4 x7 = *(const float4*)(p + 28);
    uint4 w0, w1;
    w0.x = pk4_fp8(x0.x, x0.y, x0.z, x0.w);
    w0.y = pk4_fp8(x1.x, x1.y, x1.z, x1.w);
    w0.z = pk4_fp8(x2.x, x2.y, x2.z, x2.w);
    w0.w = pk4_fp8(x3.x, x3.y, x3.z, x3.w);
    w1.x = pk4_fp8(x4.x, x4.y, x4.z, x4.w);
    w1.y = pk4_fp8(x5.x, x5.y, x5.z, x5.w);
    w1.z = pk4_fp8(x6.x, x6.y, x6.z, x6.w);
    w1.w = pk4_fp8(x7.x, x7.y, x7.z, x7.w);
    unsigned char* dst = rtf + ((size_t)b * 4096 + (size_t)u6 * 64 + lane) * 32;
    *(uint4*)dst        = w0;
    *(uint4*)(dst + 16) = w1;
}

// ------- Main: 8 waves x (64t x 32s), MX fp8 K=128, wave-rotated K-loop -------
__global__ __launch_bounds__(512, 4)
void mp_match_mx(const float* __restrict__ lt, const unsigned char* __restrict__ rtf,
                 const float* __restrict__ km, float* __restrict__ out)
{
    // stride 34 (even): every A-fragment (2 adjacent uint4) is 32B-aligned.
    __shared__ __attribute__((aligned(32))) uint4 Ash[BM * 34];   // 34.8 KB
    __shared__ __attribute__((aligned(16))) float maxbuf[8][BM];  // 2 KB

    // XCD swizzle: flat%8 == XCD; b%8 == XCD.
    const int f  = blockIdx.x;           // 0..2559
    const int c8 = f & 7;
    const int i  = f >> 3;               // 0..319
    const int b  = c8 + 8 * (i / 80);    // 0..31
    const int j  = i % 80;
    const int m  = j >> 2;               // 0..19
    const int t0 = (j & 3) * BM;         // 0,64,128,192

    const int tid  = threadIdx.x;        // 0..511
    const int w    = tid >> 6;           // wave id 0..7: owns s = w*32 .. +32
    const int lane = tid & 63;
    const int l15  = lane & 15;
    const int l4   = lane >> 4;

    const float* ltB = lt + ((size_t)b * TT + t0) * DD;
    const float* kmp = km + (size_t)m * DD;
    // step u = kk*2 + jj: B group g = w*2 + jj, s = w*32 + jj*16 + l15.
    const unsigned char* rtB0 = rtf + (size_t)b * 131072 + (size_t)(w * 128 + lane) * 32;

    i32x8 ring[2];
    auto loadB = [&](int u) {
        ring[u & 1] = *(const i32x8*)(rtB0 + (u >> 1) * 32768 + (u & 1) * 2048);
    };

    // Wave phase stagger: parity-preserving rotation; same-SIMD pairs (w,w+4)
    // get different offsets: (0,2),(2,4),(4,6),(6,0).
    const int ofs = 2 * ((w + (w >> 2)) & 3);

    loadB(ofs);   // first step of this wave's rotated order; in flight under A staging

    // ---- A staging: thread -> 8-float chunk col cc8 (d = cc8*8..+8), 8 rows.
    // 512 threads cover 64 rows x 64 chunks; fully coalesced (2KB/row/wave).
    {
        const int cc8 = tid & 63;            // 0..63
        const int r0  = (tid >> 6) * 8;      // 8 rows per thread
        const float* kp = kmp + cc8 * 8;
        const float4 k0 = *(const float4*)(kp);
        const float4 k1 = *(const float4*)(kp + 4);
#pragma unroll
        for (int r = 0; r < 8; ++r) {
            const float* src = ltB + (size_t)(r0 + r) * DD + cc8 * 8;
            float4 x0 = *(const float4*)src;
            float4 x1 = *(const float4*)(src + 4);
            uint2 o;
            o.x = pk4_fp8(x0.x * k0.x, x0.y * k0.y, x0.z * k0.z, x0.w * k0.w);
            o.y = pk4_fp8(x1.x * k1.x, x1.y * k1.y, x1.z * k1.z, x1.w * k1.w);
            unsigned* cell = (unsigned*)&Ash[(r0 + r) * 34 + (cc8 >> 1)];
            *(uint2*)(cell + (cc8 & 1) * 2) = o;
        }
    }
    __syncthreads();   // the ONLY pre-epilogue barrier (also drains loadB(ofs))

    f32x4 acc[4][2] = {};   // [ii][jj]: t = t0+ii*16+row, s = w*32 + jj*16 + col
    i32x8 av[4];

#pragma unroll
    for (int v = 0; v < 8; ++v) {
        const int u  = (v + ofs) & 7;       // rotated step; jj = u&1 = v&1 (ofs even)
        const int kk = u >> 1, jj = u & 1;
        if (v + 1 < 8) loadB((u + 1) & 7);  // lead-1 in rotated order; 2-slot ring
        if (jj == 0) {
            // A frags for this kk: row = ii*16 + l15, 32B at chunk kk*8 + l4*2.
#pragma unroll
            for (int ii = 0; ii < 4; ++ii)
                av[ii] = *(const i32x8*)&Ash[(ii * 16 + l15) * 34 + kk * 8 + l4 * 2];
        }
        const i32x8 bv = ring[u & 1];
        __builtin_amdgcn_s_setprio(1);
#pragma unroll
        for (int ii = 0; ii < 4; ++ii)
            acc[ii][jj] = __builtin_amdgcn_mfma_scale_f32_16x16x128_f8f6f4(
                av[ii], bv, acc[ii][jj], 0, 0, 0, 127, 0, 127);  // fmt=fp8, scales=1.0
        __builtin_amdgcn_s_setprio(0);
    }

    // ---- Epilogue: max over s. C layout: col(s)=lane&15, row(t)=(lane>>4)*4+reg.
#pragma unroll
    for (int ii = 0; ii < 4; ++ii) {
        f32x4 v = acc[ii][0];
        v.x = fmaxf(v.x, acc[ii][1].x);
        v.y = fmaxf(v.y, acc[ii][1].y);
        v.z = fmaxf(v.z, acc[ii][1].z);
        v.w = fmaxf(v.w, acc[ii][1].w);
#pragma unroll
        for (int off = 1; off < 16; off <<= 1) {
            v.x = fmaxf(v.x, __shfl_xor(v.x, off, 64));
            v.y = fmaxf(v.y, __shfl_xor(v.y, off, 64));
            v.z = fmaxf(v.z, __shfl_xor(v.z, off, 64));
            v.w = fmaxf(v.w, __shfl_xor(v.w, off, 64));
        }
        if (l15 == 0)
            *(f32x4*)&maxbuf[w][ii * 16 + l4 * 4] = v;
    }
    __syncthreads();
    if (tid < BM) {
        float v0 = fmaxf(fmaxf(maxbuf[0][tid], maxbuf[1][tid]),
                         fmaxf(maxbuf[2][tid], maxbuf[3][tid]));
        float v1 = fmaxf(fmaxf(maxbuf[4][tid], maxbuf[5][tid]),
                         fmaxf(maxbuf[6][tid], maxbuf[7][tid]));
        out[((size_t)b * TT + t0 + tid) * NM + m] = tanhf(fmaxf(v0, v1));
    }
}

// ---------------- R1 fallback (no workspace): bf16 MFMA, fp32 register staging ----------------
typedef short bf16x8 __attribute__((ext_vector_type(8)));

__global__ __launch_bounds__(256, 2)
void mp_match_kernel(const float* __restrict__ lt, const float* __restrict__ rt,
                     const float* __restrict__ km, float* __restrict__ out)
{
    __shared__ __attribute__((aligned(16))) unsigned short Ash[2][4][128][8];
    __shared__ __attribute__((aligned(16))) unsigned short Bsh2[2][4][256][8];
    __shared__ __attribute__((aligned(16))) float maxbuf[2][128];

    const int ttile = blockIdx.x, m = blockIdx.y, b = blockIdx.z;
    const int t0 = ttile * 128;
    const int tid = threadIdx.x, wave = tid >> 6, lane = tid & 63;
    const int l15 = lane & 15, l4 = lane >> 4;
    const int wt = (wave & 1) * 64, wsi = wave >> 1;

    const float* ltp = lt + ((size_t)b * TT + t0) * DD;
    const float* rtp = rt + (size_t)b * TT * DD;
    const float* kmp = km + (size_t)m * DD;
    const int a_t = tid >> 1, a_h = tid & 1;

    f32x4 acc[4][8] = {};

    auto stage = [&](int kk, int buf) {
        const int d0 = kk * 32;
        const float* ap = ltp + (size_t)a_t * DD + d0 + a_h * 16;
        const float* kp = kmp + d0 + a_h * 16;
#pragma unroll
        for (int q = 0; q < 2; ++q) {
            float4 x0 = *(const float4*)(ap + q * 8);
            float4 x1 = *(const float4*)(ap + q * 8 + 4);
            float4 k0 = *(const float4*)(kp + q * 8);
            float4 k1 = *(const float4*)(kp + q * 8 + 4);
            uint4 wv;
            wv.x = pack_bf16(x0.x * k0.x, x0.y * k0.y);
            wv.y = pack_bf16(x0.z * k0.z, x0.w * k0.w);
            wv.z = pack_bf16(x1.x * k1.x, x1.y * k1.y);
            wv.w = pack_bf16(x1.z * k1.z, x1.w * k1.w);
            *(uint4*)&Ash[buf][a_h * 2 + q][a_t][0] = wv;
        }
        const float* bp = rtp + (size_t)tid * DD + d0;
#pragma unroll
        for (int p = 0; p < 4; ++p) {
            float4 y0 = *(const float4*)(bp + p * 8);
            float4 y1 = *(const float4*)(bp + p * 8 + 4);
            uint4 wv;
            wv.x = pack_bf16(y0.x, y0.y);
            wv.y = pack_bf16(y0.z, y0.w);
            wv.z = pack_bf16(y1.x, y1.y);
            wv.w = pack_bf16(y1.z, y1.w);
            *(uint4*)&Bsh2[buf][p][tid][0] = wv;
        }
    };

    stage(0, 0);
    for (int kk = 0; kk < 16; ++kk) {
        const int buf = kk & 1;
        __syncthreads();
        bf16x8 af[4], bfv[8];
#pragma unroll
        for (int i2 = 0; i2 < 4; ++i2)
            af[i2] = *(const bf16x8*)&Ash[buf][l4][wt + i2 * 16 + l15][0];
#pragma unroll
        for (int j2 = 0; j2 < 8; ++j2)
            bfv[j2] = *(const bf16x8*)&Bsh2[buf][l4][wsi * 128 + j2 * 16 + l15][0];
        if (kk + 1 < 16) stage(kk + 1, buf ^ 1);
#pragma unroll
        for (int i2 = 0; i2 < 4; ++i2)
#pragma unroll
            for (int j2 = 0; j2 < 8; ++j2)
                acc[i2][j2] = __builtin_amdgcn_mfma_f32_16x16x32_bf16(af[i2], bfv[j2], acc[i2][j2], 0, 0, 0);
    }
#pragma unroll
    for (int i2 = 0; i2 < 4; ++i2) {
        f32x4 v = acc[i2][0];
#pragma unroll
        for (int j2 = 1; j2 < 8; ++j2) {
            v.x = fmaxf(v.x, acc[i2][j2].x); v.y = fmaxf(v.y, acc[i2][j2].y);
            v.z = fmaxf(v.z, acc[i2][j2].z); v.w = fmaxf(v.w, acc[i2][j2].w);
        }
#pragma unroll
        for (int off = 1; off < 16; off <<= 1) {
            v.x = fmaxf(v.x, __shfl_xor(v.x, off, 64));
            v.y = fmaxf(v.y, __shfl_xor(v.y, off, 64));
            v.z = fmaxf(v.z, __shfl_xor(v.z, off, 64));
            v.w = fmaxf(v.w, __shfl_xor(v.w, off, 64));
        }
        if (l15 == 0) *(f32x4*)&maxbuf[wsi][wt + i2 * 16 + l4 * 4] = v;
    }
    __syncthreads();
    if (tid < 128) {
        float v = fmaxf(maxbuf[0][tid], maxbuf[1][tid]);
        out[((size_t)b * TT + t0 + tid) * NM + m] = tanhf(v);
    }
}

extern "C" void kernel_launch(void* const* d_in, const int* in_sizes, int n_in,
                              void* d_out, int out_size, void* d_ws, size_t ws_size,
                              hipStream_t stream) {
    const float* lt  = (const float*)d_in[0];   // (32,256,512) fp32
    const float* rt  = (const float*)d_in[1];   // (32,256,512) fp32
    const float* km  = (const float*)d_in[2];   // (20,512) fp32
    float*       out = (float*)d_out;           // (32,256,20) fp32

    const size_t rtfB = (size_t)NB * TT * DD;   // 4,194,304 B fp8 (lane-tiled)
    if (ws_size >= rtfB) {
        unsigned char* rtf = (unsigned char*)d_ws;
        cast_rt<<<512, 256, 0, stream>>>(rt, rtf);               // XCD-aligned, proven
        mp_match_mx<<<2560, 512, 0, stream>>>(lt, rtf, km, out); // 8 waves, rotated K-loop
    } else {
        mp_match_kernel<<<dim3(2, NM, NB), 256, 0, stream>>>(lt, rt, km, out);
    }
}

// Round 12
// 108.524 us; speedup vs baseline: 1.7492x; 1.0053x over previous
//
#include <hip/hip_runtime.h>

// MpMaxPoolingMatch: out[b,t,m] = tanh( max_s sum_d lt[b,t,d]*km[m,d]*rt[b,s,d] )
// B=32, T=256, D=512, MP=20.
// R22 = R13 base + CU-memory-path byte cuts. Post-mortem synthesis R10-R21:
// single-factor theories all null (VALU, B-latency, occupancy, traffic,
// phase-lock); per-CU pipe totals show the wall = SUM of shared-path costs:
// LDS pipe ~45k cy (A-frag 8x re-read + epilogue ds_swizzle shfls + conflicts),
// L1/TA ~40k cy (258KB/block: lt fp32 128KB + B 128KB), VALU ~38k, MFMA 22k;
// wall 108k. Blocks self-limit to ~1.3 concurrent because more would
// oversubscribe LDS+L1. So: cut bytes/ops through the CU:
//  1) lt->bf16 pre-pass restored (R10 cast): A-side reads 128->64KB/block
//     (lt re-read 20x: 320->160MB kernel-wide), A-VMEM inst count halved.
//  2) DPP epilogue: row_ror 1/2/4/8 + v_max (pure VALU) replaces 64 shfl_xor
//     (ds_swizzle on the LDS pipe + serial lgkm chains).
//  3) setprio kept around MFMA cluster (R21 best-of).
// Structure, rtf layout, Ash stride-34, 4-slot/lead-3 B ring, MFMA operand
// bytes/scales (e8m0=127): identical to R13 (proven 44.5us, absmax 0.0).

constexpr int TT = 256;   // T
constexpr int DD = 512;   // D
constexpr int NM = 20;    // MP
constexpr int NB = 32;    // B
constexpr int BM = 64;    // t-tile
constexpr int NK = 4;     // K-steps of 128

typedef float f32x4 __attribute__((ext_vector_type(4)));
typedef int   i32x8 __attribute__((ext_vector_type(8)));

__device__ __forceinline__ unsigned pack_bf16(float lo, float hi) {
    unsigned ulo = __builtin_bit_cast(unsigned, lo);
    unsigned uhi = __builtin_bit_cast(unsigned, hi);
    return (ulo >> 16) | (uhi & 0xFFFF0000u);
}
__device__ __forceinline__ float blo(unsigned u) { return __builtin_bit_cast(float, u << 16); }
// hi bf16 without masking low bits: <0.4% perturbation, absorbed by fp8 quant +
// tanh saturation (R10-R13 proven, absmax 0.0).
__device__ __forceinline__ float bhi(unsigned u) { return __builtin_bit_cast(float, u); }

// 4 fp32 -> 4 fp8 (e4m3, packed dword)
__device__ __forceinline__ unsigned pk4_fp8(float a, float b, float c, float d) {
    unsigned r = __builtin_amdgcn_cvt_pk_fp8_f32(a, b, 0, false);
    return __builtin_amdgcn_cvt_pk_fp8_f32(c, d, r, true);
}

// max over each 16-lane row via DPP row_ror (VALU only; no LDS pipe, no lgkm).
__device__ __forceinline__ float row_max16(float v) {
    int t;
    t = __builtin_amdgcn_update_dpp(0, __builtin_bit_cast(int, v), 0x121, 0xf, 0xf, true); // ror:1
    v = fmaxf(v, __builtin_bit_cast(float, t));
    t = __builtin_amdgcn_update_dpp(0, __builtin_bit_cast(int, v), 0x122, 0xf, 0xf, true); // ror:2
    v = fmaxf(v, __builtin_bit_cast(float, t));
    t = __builtin_amdgcn_update_dpp(0, __builtin_bit_cast(int, v), 0x124, 0xf, 0xf, true); // ror:4
    v = fmaxf(v, __builtin_bit_cast(float, t));
    t = __builtin_amdgcn_update_dpp(0, __builtin_bit_cast(int, v), 0x128, 0xf, 0xf, true); // ror:8
    v = fmaxf(v, __builtin_bit_cast(float, t));
    return v;
}

// ---------------- Phase 1: lt fp32->bf16 row-major; rt fp32->fp8 lane-tiled ----------
// rtf layout: 32B element e = (b*4096 + (kk*16+g)*64 + lane):
//   holds rt[b][s = g*16 + (lane&15)][d = kk*128 + (lane>>4)*32 .. +32] as fp8.
__global__ __launch_bounds__(256)
void cast_inputs(const float* __restrict__ lt, const float* __restrict__ rt,
                 unsigned short* __restrict__ ltb, unsigned char* __restrict__ rtf)
{
    const int bid = (int)blockIdx.x;
    const int tid = threadIdx.x;
    if (bid < 2048) {
        // lt -> bf16, plain row-major, 8 elems/thread.
        size_t base = ((size_t)bid * 256 + tid) * 8;
        float4 a = *(const float4*)(lt + base);
        float4 b = *(const float4*)(lt + base + 4);
        uint4 w;
        w.x = pack_bf16(a.x, a.y);
        w.y = pack_bf16(a.z, a.w);
        w.z = pack_bf16(b.x, b.y);
        w.w = pack_bf16(b.z, b.w);
        *(uint4*)(ltb + base) = w;
    } else {
        // rt -> fp8 tiled, XCD-aligned (bid2&7 == bid&7 since 2048%8==0).
        const int bid2 = bid - 2048;           // 0..511
        const int c8   = bid2 & 7;
        const int i    = bid2 >> 3;            // 0..63
        const int b    = c8 + 8 * (i & 3);     // b%8 == consumer XCD
        const int sub  = i >> 2;               // 0..15
        const int lane = tid & 63;
        const int u6   = sub * 4 + (tid >> 6); // 0..63 == kk*16 + g
        const int s    = (u6 & 15) * 16 + (lane & 15);
        const int d0   = (u6 >> 4) * 128 + (lane >> 4) * 32;

        const float* p = rt + ((size_t)b * TT + s) * DD + d0;
        float4 x0 = *(const float4*)p;
        float4 x1 = *(const float4*)(p + 4);
        float4 x2 = *(const float4*)(p + 8);
        float4 x3 = *(const float4*)(p + 12);
        float4 x4 = *(const float4*)(p + 16);
        float4 x5 = *(const float4*)(p + 20);
        float4 x6 = *(const float4*)(p + 24);
        float4 x7 = *(const float4*)(p + 28);
        uint4 w0, w1;
        w0.x = pk4_fp8(x0.x, x0.y, x0.z, x0.w);
        w0.y = pk4_fp8(x1.x, x1.y, x1.z, x1.w);
        w0.z = pk4_fp8(x2.x, x2.y, x2.z, x2.w);
        w0.w = pk4_fp8(x3.x, x3.y, x3.z, x3.w);
        w1.x = pk4_fp8(x4.x, x4.y, x4.z, x4.w);
        w1.y = pk4_fp8(x5.x, x5.y, x5.z, x5.w);
        w1.z = pk4_fp8(x6.x, x6.y, x6.z, x6.w);
        w1.w = pk4_fp8(x7.x, x7.y, x7.z, x7.w);
        unsigned char* dst = rtf + ((size_t)b * 4096 + (size_t)u6 * 64 + lane) * 32;
        *(uint4*)dst        = w0;
        *(uint4*)(dst + 16) = w1;
    }
}

// ---------------- Main: 64t x 256s, MX fp8 K=128, bf16 A source, DPP epilogue --------
__global__ __launch_bounds__(256, 2)
void mp_match_mx(const unsigned short* __restrict__ ltb, const unsigned char* __restrict__ rtf,
                 const float* __restrict__ km, float* __restrict__ out)
{
    // stride 34 (even): every A-fragment (2 adjacent uint4) is 32B-aligned.
    __shared__ __attribute__((aligned(32))) uint4 Ash[BM * 34];   // 34.8 KB
    __shared__ __attribute__((aligned(16))) float maxbuf[4][BM];  // 1 KB

    // XCD swizzle: flat%8 == XCD; b%8 == XCD.
    const int f  = blockIdx.x;           // 0..2559
    const int c8 = f & 7;
    const int i  = f >> 3;               // 0..319
    const int b  = c8 + 8 * (i / 80);    // 0..31
    const int j  = i % 80;
    const int m  = j >> 2;               // 0..19
    const int t0 = (j & 3) * BM;         // 0,64,128,192

    const int tid  = threadIdx.x;
    const int w    = tid >> 6;           // wave id = s-quarter owner
    const int lane = tid & 63;
    const int l15  = lane & 15;
    const int l4   = lane >> 4;

    const unsigned short* ltB = ltb + ((size_t)b * TT + t0) * DD;
    const float*          kmp = km  + (size_t)m * DD;
    // step u = kk*4+q: one 32B contiguous load per lane at rtB0 + u*8192.
    const unsigned char*  rtB0 = rtf + (size_t)b * 131072 + (size_t)(w * 64 + lane) * 32;

    i32x8 ring[4];
    auto loadB = [&](int u) {
        ring[u & 3] = *(const i32x8*)(rtB0 + u * 8192);
    };

    // 3-deep prologue: in flight under the whole A conversion.
    loadB(0); loadB(1); loadB(2);

    // ---- A staging: thread -> chunk-col cc (d = cc*16..+16), rows r0..r0+8.
    // Reads ltb bf16 (16B/row/thread, half of fp32), fuses *km + fp8.
    const int cc = tid & 31, r0 = (tid >> 5) * 8;
    const float4 kA = *(const float4*)(kmp + cc * 16);
    const float4 kB = *(const float4*)(kmp + cc * 16 + 4);
    const float4 kC = *(const float4*)(kmp + cc * 16 + 8);
    const float4 kD = *(const float4*)(kmp + cc * 16 + 12);
#pragma unroll
    for (int r = 0; r < 8; ++r) {
        const unsigned short* src = ltB + (size_t)(r0 + r) * DD + cc * 16;
        uint4 h0 = *(const uint4*)src;        // bf16 d..d+7
        uint4 h1 = *(const uint4*)(src + 8);  // bf16 d+8..d+15
        uint4 o;
        o.x = pk4_fp8(blo(h0.x) * kA.x, bhi(h0.x) * kA.y, blo(h0.y) * kA.z, bhi(h0.y) * kA.w);
        o.y = pk4_fp8(blo(h0.z) * kB.x, bhi(h0.z) * kB.y, blo(h0.w) * kB.z, bhi(h0.w) * kB.w);
        o.z = pk4_fp8(blo(h1.x) * kC.x, bhi(h1.x) * kC.y, blo(h1.y) * kC.z, bhi(h1.y) * kC.w);
        o.w = pk4_fp8(blo(h1.z) * kD.x, bhi(h1.z) * kD.y, blo(h1.w) * kD.z, bhi(h1.w) * kD.w);
        Ash[(r0 + r) * 34 + cc] = o;
    }
    __syncthreads();   // the ONLY pre-epilogue barrier (also drains loadB(0..2))

    f32x4 acc[4][4] = {};   // [ii][q]: t = t0+ii*16+..., s = q*64 + w*16 + ...
    i32x8 av[4];

#pragma unroll
    for (int u = 0; u < 16; ++u) {
        const int kk = u >> 2, q = u & 3;
        if (u + 3 < 16) loadB(u + 3);   // lead-3; 4-slot ring (R13 proven)
        if (q == 0) {
            // A frags for this kk: row = ii*16 + l15, 32B at chunk kk*8 + l4*2.
#pragma unroll
            for (int ii = 0; ii < 4; ++ii)
                av[ii] = *(const i32x8*)&Ash[(ii * 16 + l15) * 34 + kk * 8 + l4 * 2];
        }
        const i32x8 bv = ring[u & 3];
        __builtin_amdgcn_s_setprio(1);
#pragma unroll
        for (int ii = 0; ii < 4; ++ii)
            acc[ii][q] = __builtin_amdgcn_mfma_scale_f32_16x16x128_f8f6f4(
                av[ii], bv, acc[ii][q], 0, 0, 0, 127, 0, 127);  // fmt=fp8, scales=1.0
        __builtin_amdgcn_s_setprio(0);
    }

    // ---- Epilogue: max over s, DPP row-reduce (VALU pipe; no LDS shfl chains).
    // C layout: col(s)=lane&15, row(t)=(lane>>4)*4+reg.
#pragma unroll
    for (int ii = 0; ii < 4; ++ii) {
        f32x4 v = acc[ii][0];
#pragma unroll
        for (int q = 1; q < 4; ++q) {
            v.x = fmaxf(v.x, acc[ii][q].x);
            v.y = fmaxf(v.y, acc[ii][q].y);
            v.z = fmaxf(v.z, acc[ii][q].z);
            v.w = fmaxf(v.w, acc[ii][q].w);
        }
        v.x = row_max16(v.x);
        v.y = row_max16(v.y);
        v.z = row_max16(v.z);
        v.w = row_max16(v.w);
        if (l15 == 0)
            *(f32x4*)&maxbuf[w][ii * 16 + l4 * 4] = v;
    }
    __syncthreads();
    if (tid < BM) {
        float v = fmaxf(fmaxf(maxbuf[0][tid], maxbuf[1][tid]),
                        fmaxf(maxbuf[2][tid], maxbuf[3][tid]));
        out[((size_t)b * TT + t0 + tid) * NM + m] = tanhf(v);
    }
}

// ---------------- R1 fallback (no workspace): bf16 MFMA, fp32 register staging ----------------
typedef short bf16x8 __attribute__((ext_vector_type(8)));

__global__ __launch_bounds__(256, 2)
void mp_match_kernel(const float* __restrict__ lt, const float* __restrict__ rt,
                     const float* __restrict__ km, float* __restrict__ out)
{
    __shared__ __attribute__((aligned(16))) unsigned short Ash[2][4][128][8];
    __shared__ __attribute__((aligned(16))) unsigned short Bsh2[2][4][256][8];
    __shared__ __attribute__((aligned(16))) float maxbuf[2][128];

    const int ttile = blockIdx.x, m = blockIdx.y, b = blockIdx.z;
    const int t0 = ttile * 128;
    const int tid = threadIdx.x, wave = tid >> 6, lane = tid & 63;
    const int l15 = lane & 15, l4 = lane >> 4;
    const int wt = (wave & 1) * 64, wsi = wave >> 1;

    const float* ltp = lt + ((size_t)b * TT + t0) * DD;
    const float* rtp = rt + (size_t)b * TT * DD;
    const float* kmp = km + (size_t)m * DD;
    const int a_t = tid >> 1, a_h = tid & 1;

    f32x4 acc[4][8] = {};

    auto stage = [&](int kk, int buf) {
        const int d0 = kk * 32;
        const float* ap = ltp + (size_t)a_t * DD + d0 + a_h * 16;
        const float* kp = kmp + d0 + a_h * 16;
#pragma unroll
        for (int q = 0; q < 2; ++q) {
            float4 x0 = *(const float4*)(ap + q * 8);
            float4 x1 = *(const float4*)(ap + q * 8 + 4);
            float4 k0 = *(const float4*)(kp + q * 8);
            float4 k1 = *(const float4*)(kp + q * 8 + 4);
            uint4 wv;
            wv.x = pack_bf16(x0.x * k0.x, x0.y * k0.y);
            wv.y = pack_bf16(x0.z * k0.z, x0.w * k0.w);
            wv.z = pack_bf16(x1.x * k1.x, x1.y * k1.y);
            wv.w = pack_bf16(x1.z * k1.z, x1.w * k1.w);
            *(uint4*)&Ash[buf][a_h * 2 + q][a_t][0] = wv;
        }
        const float* bp = rtp + (size_t)tid * DD + d0;
#pragma unroll
        for (int p = 0; p < 4; ++p) {
            float4 y0 = *(const float4*)(bp + p * 8);
            float4 y1 = *(const float4*)(bp + p * 8 + 4);
            uint4 wv;
            wv.x = pack_bf16(y0.x, y0.y);
            wv.y = pack_bf16(y0.z, y0.w);
            wv.z = pack_bf16(y1.x, y1.y);
            wv.w = pack_bf16(y1.z, y1.w);
            *(uint4*)&Bsh2[buf][p][tid][0] = wv;
        }
    };

    stage(0, 0);
    for (int kk = 0; kk < 16; ++kk) {
        const int buf = kk & 1;
        __syncthreads();
        bf16x8 af[4], bfv[8];
#pragma unroll
        for (int i2 = 0; i2 < 4; ++i2)
            af[i2] = *(const bf16x8*)&Ash[buf][l4][wt + i2 * 16 + l15][0];
#pragma unroll
        for (int j2 = 0; j2 < 8; ++j2)
            bfv[j2] = *(const bf16x8*)&Bsh2[buf][l4][wsi * 128 + j2 * 16 + l15][0];
        if (kk + 1 < 16) stage(kk + 1, buf ^ 1);
#pragma unroll
        for (int i2 = 0; i2 < 4; ++i2)
#pragma unroll
            for (int j2 = 0; j2 < 8; ++j2)
                acc[i2][j2] = __builtin_amdgcn_mfma_f32_16x16x32_bf16(af[i2], bfv[j2], acc[i2][j2], 0, 0, 0);
    }
#pragma unroll
    for (int i2 = 0; i2 < 4; ++i2) {
        f32x4 v = acc[i2][0];
#pragma unroll
        for (int j2 = 1; j2 < 8; ++j2) {
            v.x = fmaxf(v.x, acc[i2][j2].x); v.y = fmaxf(v.y, acc[i2][j2].y);
            v.z = fmaxf(v.z, acc[i2][j2].z); v.w = fmaxf(v.w, acc[i2][j2].w);
        }
#pragma unroll
        for (int off = 1; off < 16; off <<= 1) {
            v.x = fmaxf(v.x, __shfl_xor(v.x, off, 64));
            v.y = fmaxf(v.y, __shfl_xor(v.y, off, 64));
            v.z = fmaxf(v.z, __shfl_xor(v.z, off, 64));
            v.w = fmaxf(v.w, __shfl_xor(v.w, off, 64));
        }
        if (l15 == 0) *(f32x4*)&maxbuf[wsi][wt + i2 * 16 + l4 * 4] = v;
    }
    __syncthreads();
    if (tid < 128) {
        float v = fmaxf(maxbuf[0][tid], maxbuf[1][tid]);
        out[((size_t)b * TT + t0 + tid) * NM + m] = tanhf(v);
    }
}

extern "C" void kernel_launch(void* const* d_in, const int* in_sizes, int n_in,
                              void* d_out, int out_size, void* d_ws, size_t ws_size,
                              hipStream_t stream) {
    const float* lt  = (const float*)d_in[0];   // (32,256,512) fp32
    const float* rt  = (const float*)d_in[1];   // (32,256,512) fp32
    const float* km  = (const float*)d_in[2];   // (20,512) fp32
    float*       out = (float*)d_out;           // (32,256,20) fp32

    const size_t elems = (size_t)NB * TT * DD;                 // 4,194,304
    const size_t ltbB  = elems * sizeof(unsigned short);       // 8.39 MB bf16
    const size_t rtfB  = elems;                                // 4.19 MB fp8 (tiled)

    if (ws_size >= ltbB + rtfB) {                              // 12.6 MB
        unsigned short* ltb = (unsigned short*)d_ws;
        unsigned char*  rtf = (unsigned char*)((char*)d_ws + ltbB);
        cast_inputs<<<2560, 256, 0, stream>>>(lt, rt, ltb, rtf);
        mp_match_mx<<<2560, 256, 0, stream>>>(ltb, rtf, km, out);
    } else {
        mp_match_kernel<<<dim3(2, NM, NB), 256, 0, stream>>>(lt, rt, km, out);
    }
}